// Round 1
// baseline (5445.339 us; speedup 1.0000x reference)
//
#include <hip/hip_runtime.h>
#include <hip/hip_bf16.h>
#include <cstdint>
#include <cstddef>

#define DI __device__ __forceinline__

typedef __attribute__((ext_vector_type(8))) short          bf16x8;
typedef __attribute__((ext_vector_type(8))) unsigned short u16x8;
typedef __attribute__((ext_vector_type(4))) float          f32x4;

// ---- problem constants ----
constexpr int Sv = 512, Bv = 128, Dv = 512, Hv = 256;
constexpr int Mv = Sv * Bv;   // 65536 GEMM rows

// ---- workspace layout (bytes) ----
constexpr size_t SZ_HSUM   = (size_t)Bv * (Sv + 1) * Hv * 4;   // 67,239,936
constexpr size_t OFF_HSUM  = 0;
constexpr size_t OFF_FCSUM = SZ_HSUM;
constexpr size_t OFF_CNT   = 2 * SZ_HSUM;
constexpr size_t MEMSET_BYTES = 2 * SZ_HSUM + 4096;            // hsum+fcsum+counters
constexpr size_t OFF_HX    = MEMSET_BYTES;                     // 2*32*4*256*4 = 262144
constexpr size_t OFF_XIOU  = OFF_HX + 262144;
constexpr size_t OFF_XF    = OFF_XIOU + (size_t)Mv * 768 * 4;  // 201,326,592
constexpr size_t OFF_BTH   = OFF_XF + (size_t)Mv * 256 * 4;    //  67,108,864
constexpr size_t OFF_BTL   = OFF_BTH + (size_t)1024 * 512 * 2; //   1,048,576
// total ~405 MB

DI unsigned short f2bf(float x) {  // RNE float->bf16 bits
  union { float f; uint32_t u; } v; v.f = x;
  uint32_t r = v.u + 0x7fffu + ((v.u >> 16) & 1u);
  return (unsigned short)(r >> 16);
}
DI float bf2f(unsigned short b) {
  union { uint32_t u; float f; } v; v.u = ((uint32_t)b) << 16; return v.f;
}
DI float sigm(float x) { return 1.0f / (1.0f + __expf(-x)); }

// =============== W transpose + bf16 hi/lo split: BT[n][k], n in [0,1024) ===============
__global__ void cvt_w_kernel(const float* __restrict__ Wiou, const float* __restrict__ Wf,
                             unsigned short* __restrict__ bth, unsigned short* __restrict__ btl)
{
  int idx = blockIdx.x * 256 + threadIdx.x;  // 1024*512 threads
  int n = idx >> 9, k = idx & 511;
  float v = (n < 768) ? Wiou[(size_t)k * 768 + n] : Wf[(size_t)k * 256 + (n - 768)];
  unsigned short h = f2bf(v);
  bth[idx] = h;
  btl[idx] = f2bf(v - bf2f(h));
}

// =============== split-bf16 GEMM: x = inputs @ [W_iou|W_f] + bias (3-term, fp32-accurate) ===============
#define GLD_LDS16(gp, lp) __builtin_amdgcn_global_load_lds( \
    (const __attribute__((address_space(1))) unsigned int*)(gp), \
    (__attribute__((address_space(3))) unsigned int*)(lp), 16, 0, 0)

__global__ __launch_bounds__(256, 2)
void gemm_split_kernel(const float* __restrict__ A,
                       const unsigned short* __restrict__ BTh,
                       const unsigned short* __restrict__ BTl,
                       const float* __restrict__ biou, const float* __restrict__ bfv,
                       float* __restrict__ xiou, float* __restrict__ xf)
{
  extern __shared__ char lds[];
  unsigned short* As = (unsigned short*)lds;             // [2][128][64] bf16
  unsigned short* Bs = (unsigned short*)(lds + 32768);   // [2][128][64] bf16

  const int bid = blockIdx.x;
  const int ntile = bid & 7, mtile = bid >> 3;
  const int m0 = mtile * 128, n0 = ntile * 128;
  const int tid = threadIdx.x;
  const int lane = tid & 63, w = tid >> 6;
  const int wr = w >> 1, wc = w & 1;

  f32x4 acc[4][4];
  #pragma unroll
  for (int i = 0; i < 4; i++)
    #pragma unroll
    for (int jj = 0; jj < 4; jj++) acc[i][jj] = f32x4{0.f, 0.f, 0.f, 0.f};

  const int arow = tid >> 1, ahalf = tid & 1;
  float areg[32];

  auto issueA = [&](int kk0) {
    const float* g = A + (size_t)(m0 + arow) * 512 + kk0 + ahalf * 32;
    #pragma unroll
    for (int i = 0; i < 8; i++) {
      f32x4 v = ((const f32x4*)g)[i];
      areg[i * 4 + 0] = v[0]; areg[i * 4 + 1] = v[1];
      areg[i * 4 + 2] = v[2]; areg[i * 4 + 3] = v[3];
    }
  };
  auto writeA = [&](int buf, int low) {
    unsigned short* dst = As + buf * 8192 + arow * 64 + ahalf * 32;
    #pragma unroll
    for (int i = 0; i < 4; i++) {
      u16x8 o;
      #pragma unroll
      for (int jj = 0; jj < 8; jj++) {
        float x = areg[i * 8 + jj];
        unsigned short h = f2bf(x);
        o[jj] = low ? f2bf(x - bf2f(h)) : h;
      }
      *(u16x8*)(dst + i * 8) = o;
    }
  };
  auto stageB = [&](int buf, const unsigned short* Bbase, int kk0) {
    #pragma unroll
    for (int q = 0; q < 4; q++) {
      int cidx = q * 256 + tid;
      int row = cidx >> 3, blk = cidx & 7;
      const unsigned short* g = Bbase + (size_t)(n0 + row) * 512 + kk0 + blk * 8;
      unsigned short* l = Bs + buf * 8192 + cidx * 8;
      GLD_LDS16(g, l);
    }
  };
  // tiles t=0..23: term = t>>3 : 0=(Ah,Bh) 1=(Al,Bh) 2=(Ah,Bl); k0 = (t&7)*64
  auto alow = [](int t) { return ((t >> 3) == 1) ? 1 : 0; };

  issueA(0);
  stageB(0, BTh, 0);
  asm volatile("s_waitcnt vmcnt(0)" ::: "memory");
  writeA(0, alow(0));
  __syncthreads();

  for (int t = 0; t < 24; ++t) {
    const int buf = t & 1;
    if (t < 23) {
      const int tn = t + 1;
      issueA((tn & 7) * 64);
      stageB(buf ^ 1, (tn < 16) ? BTh : BTl, (tn & 7) * 64);
    }
    #pragma unroll
    for (int kk = 0; kk < 64; kk += 32) {
      const int k8 = (lane >> 4) * 8;
      bf16x8 af[4], bfrag[4];
      #pragma unroll
      for (int mi = 0; mi < 4; ++mi)
        af[mi] = *(const bf16x8*)(As + buf * 8192 + (size_t)(wr * 64 + mi * 16 + (lane & 15)) * 64 + kk + k8);
      #pragma unroll
      for (int ni = 0; ni < 4; ++ni)
        bfrag[ni] = *(const bf16x8*)(Bs + buf * 8192 + (size_t)(wc * 64 + ni * 16 + (lane & 15)) * 64 + kk + k8);
      #pragma unroll
      for (int mi = 0; mi < 4; ++mi)
        #pragma unroll
        for (int ni = 0; ni < 4; ++ni)
          acc[mi][ni] = __builtin_amdgcn_mfma_f32_16x16x32_bf16(af[mi], bfrag[ni], acc[mi][ni], 0, 0, 0);
    }
    if (t < 23) {
      asm volatile("s_waitcnt vmcnt(0)" ::: "memory");
      writeA(buf ^ 1, alow(t + 1));
    }
    __syncthreads();
  }

  const bool isiou = (n0 < 768);  // block-uniform
  #pragma unroll
  for (int ni = 0; ni < 4; ++ni) {
    int coln = n0 + wc * 64 + ni * 16 + (lane & 15);
    float bv = isiou ? biou[coln] : bfv[coln - 768];
    float* dst = isiou ? (xiou + coln) : (xf + (coln - 768));
    const int ld = isiou ? 768 : 256;
    #pragma unroll
    for (int mi = 0; mi < 4; ++mi)
      #pragma unroll
      for (int r = 0; r < 4; ++r) {
        int rowm = m0 + wr * 64 + mi * 16 + (lane >> 4) * 4 + r;
        dst[(size_t)rowm * ld] = acc[mi][ni][r] + bv;
      }
  }
}

// =============== sequential scan: 32 groups x 4 batches; 8 column-split wgs per group ===============
// wg (g=bid&31, j=bid>>5) owns H-slice [j*32, j*32+32): U_iou cols {i,o,u}x32 + U_f cols 32, fp32 in LDS.
// Cross-wg data (h exchange, hsum) via agent-scope atomics (L3-coherent, XCD-safe).
__global__ __launch_bounds__(256, 1)
void scan_kernel(const float* __restrict__ xiou, const float* __restrict__ xf,
                 const int* __restrict__ parents,
                 const float* __restrict__ Uiou, const float* __restrict__ Uf,
                 float* hsum, float* fcsum, float* hx, int* cnt,
                 float* __restrict__ out)
{
  extern __shared__ char lds[];
  float* UT   = (float*)lds;                 // [128 lc][256 m], col-major, m4 XOR-swizzled
  float* htb  = (float*)(lds + 131072);      // [4][256]
  float* hfb  = (float*)(lds + 135168);      // [4][256]
  float* red  = (float*)(lds + 139264);      // [128 lc][2 mh][4 b]
  float* cbuf = (float*)(lds + 143360);      // [4][32]

  const int bid = blockIdx.x;
  const int g = bid & 31, j = bid >> 5;
  const int tid = threadIdx.x;
  const int lane = tid & 63, w = tid >> 6;
  const int b0 = g * 4;

  // load U slice into LDS (once): lc = gate*32 + hc; gate 0..2 -> U_iou, 3 -> U_f
  for (int it = 0; it < 128; ++it) {
    int idx = it * 256 + tid;
    int m = idx >> 7, lc = idx & 127;
    int gate = lc >> 5, hc = lc & 31;
    float v = (gate < 3) ? Uiou[(size_t)m * 768 + gate * 256 + j * 32 + hc]
                         : Uf[(size_t)m * 256 + j * 32 + hc];
    UT[lc * 256 + (((m >> 2) ^ (lc & 7)) << 2) + (m & 3)] = v;
  }
  __syncthreads();

  int* cg = cnt + g;
  // iou GEMV mapping: wave -> (col-half, m-half); lane -> local col
  const int cgx = w & 1, mh = w >> 1;
  const int lc = cgx * 64 + lane;
  const float* utrow = UT + lc * 256;
  const int sw = lc & 7;
  // f GEMV mapping: wave=batch; lane -> (hc, m-half)
  const int fb = w, fhc = lane & 31, fmh = lane >> 5;
  const float* ufrow = UT + (96 + fhc) * 256;
  const int fsw = (96 + fhc) & 7;
  // activation mapping (tid<128): (batch, hc)
  const int ab = tid >> 5, ahc = tid & 31;
  const int abg = b0 + ab;
  const int ahcol = j * 32 + ahc;

  #pragma unroll 1
  for (int s = 0; s < 512; ++s) {
    // prefetch read-only per-step data (held in regs across the step)
    float xg_i = 0.f, xg_o = 0.f, xg_u = 0.f;
    int p_act = 0;
    if (tid < 128) {
      size_t xrow = ((size_t)s * 128 + abg) * 768;
      xg_i = xiou[xrow + ahcol];
      xg_o = xiou[xrow + 256 + ahcol];
      xg_u = xiou[xrow + 512 + ahcol];
      p_act = parents[abg * 512 + s];
    }
    const int p_f = parents[(b0 + fb) * 512 + s];

    // ---- stage ht = hsum[:, s] (peers' slices -> L3-coherent loads) ----
    #pragma unroll
    for (int q = 0; q < 4; q++) {
      int idx = q * 256 + tid;
      int b = idx >> 8, m = idx & 255;
      htb[b * 256 + m] = __hip_atomic_load(&hsum[((size_t)(b0 + b) * 513 + s) * 256 + m],
                                           __ATOMIC_RELAXED, __HIP_MEMORY_SCOPE_AGENT);
    }
    __syncthreads();

    // fct: own slice; ordered vs prev step's f-phase by the barrier above
    float fct = 0.f;
    if (tid < 128) fct = fcsum[((size_t)abg * 513 + s) * 256 + ahcol];

    // ---- GEMV iou: g_partial[lc] = sum_m ht[b][m] * U[m][lc] (lanes lc>=96 compute unused values) ----
    {
      f32x4 a = {0.f, 0.f, 0.f, 0.f};
      #pragma unroll 8
      for (int m4 = mh * 32; m4 < mh * 32 + 32; ++m4) {
        f32x4 u = *(const f32x4*)(utrow + ((m4 ^ sw) << 2));
        const float* hb = htb + m4 * 4;
        f32x4 h0 = *(const f32x4*)(hb);
        f32x4 h1 = *(const f32x4*)(hb + 256);
        f32x4 h2 = *(const f32x4*)(hb + 512);
        f32x4 h3 = *(const f32x4*)(hb + 768);
        a[0] += u[0]*h0[0] + u[1]*h0[1] + u[2]*h0[2] + u[3]*h0[3];
        a[1] += u[0]*h1[0] + u[1]*h1[1] + u[2]*h1[2] + u[3]*h1[3];
        a[2] += u[0]*h2[0] + u[1]*h2[1] + u[2]*h2[2] + u[3]*h2[3];
        a[3] += u[0]*h3[0] + u[1]*h3[1] + u[2]*h3[2] + u[3]*h3[3];
      }
      *(f32x4*)(red + lc * 8 + mh * 4) = a;
    }
    __syncthreads();

    // ---- activations; write h to contexts, hsum scatter (atomic), h-exchange ----
    if (tid < 128) {
      float gi = xg_i + red[ahc * 8 + ab]        + red[ahc * 8 + 4 + ab];
      float go = xg_o + red[(32 + ahc) * 8 + ab] + red[(32 + ahc) * 8 + 4 + ab];
      float gu = xg_u + red[(64 + ahc) * 8 + ab] + red[(64 + ahc) * 8 + 4 + ab];
      float iv = sigm(gi), ov = sigm(go), uv = tanhf(gu);
      float c = iv * uv + fct;
      float h = ov * tanhf(c);
      cbuf[ab * 32 + ahc] = c;
      out[((size_t)s * 128 + abg) * 256 + ahcol] = h;
      if (s == 511) out[(size_t)512 * 128 * 256 + (size_t)abg * 256 + ahcol] = h;
      __hip_atomic_fetch_add(&hsum[((size_t)abg * 513 + p_act) * 256 + ahcol], h,
                             __ATOMIC_RELAXED, __HIP_MEMORY_SCOPE_AGENT);
      __hip_atomic_store(&hx[((size_t)(s & 1) * 128 + g * 4 + ab) * 256 + ahcol], h,
                         __ATOMIC_RELAXED, __HIP_MEMORY_SCOPE_AGENT);
    }
    asm volatile("s_waitcnt vmcnt(0)" ::: "memory");  // drain all vmem before arrival
    __syncthreads();
    if (tid == 0) {
      __hip_atomic_fetch_add(cg, 1, __ATOMIC_RELAXED, __HIP_MEMORY_SCOPE_AGENT);
      const int target = 8 * (s + 1);
      while (__hip_atomic_load(cg, __ATOMIC_RELAXED, __HIP_MEMORY_SCOPE_AGENT) < target) { }
    }
    __syncthreads();

    // ---- stage full h of this step (assembled from 8 wgs) ----
    #pragma unroll
    for (int q = 0; q < 4; q++) {
      int idx = q * 256 + tid;
      int b = idx >> 8, m = idx & 255;
      hfb[b * 256 + m] = __hip_atomic_load(&hx[((size_t)(s & 1) * 128 + g * 4 + b) * 256 + m],
                                           __ATOMIC_RELAXED, __HIP_MEMORY_SCOPE_AGENT);
    }
    __syncthreads();

    // ---- GEMV f + fcsum scatter (own slice, plain RMW) ----
    {
      float fa = 0.f;
      const float* hb = hfb + fb * 256;
      #pragma unroll 8
      for (int m4 = fmh * 32; m4 < fmh * 32 + 32; ++m4) {
        f32x4 u = *(const f32x4*)(ufrow + ((m4 ^ fsw) << 2));
        f32x4 h4 = *(const f32x4*)(hb + m4 * 4);
        fa += u[0]*h4[0] + u[1]*h4[1] + u[2]*h4[2] + u[3]*h4[3];
      }
      fa += __shfl_xor(fa, 32);
      if (fmh == 0) {
        float xfv = (p_f < 512) ? xf[((size_t)p_f * 128 + (b0 + fb)) * 256 + j * 32 + fhc] : 0.f;
        float fgate = sigm(xfv + fa);
        float fc = fgate * cbuf[fb * 32 + fhc];
        size_t fi = ((size_t)(b0 + fb) * 513 + p_f) * 256 + j * 32 + fhc;
        fcsum[fi] += fc;
      }
    }
  }
}

extern "C" void kernel_launch(void* const* d_in, const int* in_sizes, int n_in,
                              void* d_out, int out_size, void* d_ws, size_t ws_size,
                              hipStream_t stream)
{
  (void)in_sizes; (void)n_in; (void)out_size; (void)ws_size;
  const float* inputs  = (const float*)d_in[0];
  const int*   parents = (const int*)d_in[1];
  const float* Wiou    = (const float*)d_in[2];
  const float* biou    = (const float*)d_in[3];
  const float* Uiou    = (const float*)d_in[4];
  const float* Wf      = (const float*)d_in[5];
  const float* bf_     = (const float*)d_in[6];
  const float* Uf      = (const float*)d_in[7];
  float* out = (float*)d_out;
  char* ws = (char*)d_ws;

  float* hsum  = (float*)(ws + OFF_HSUM);
  float* fcsum = (float*)(ws + OFF_FCSUM);
  int*   cnt   = (int*)(ws + OFF_CNT);
  float* hx    = (float*)(ws + OFF_HX);
  float* xiou  = (float*)(ws + OFF_XIOU);
  float* xf    = (float*)(ws + OFF_XF);
  unsigned short* bth = (unsigned short*)(ws + OFF_BTH);
  unsigned short* btl = (unsigned short*)(ws + OFF_BTL);

  hipMemsetAsync(ws, 0, MEMSET_BYTES, stream);

  hipFuncSetAttribute((const void*)gemm_split_kernel,
                      hipFuncAttributeMaxDynamicSharedMemorySize, 65536);
  hipFuncSetAttribute((const void*)scan_kernel,
                      hipFuncAttributeMaxDynamicSharedMemorySize, 147456);

  cvt_w_kernel<<<2048, 256, 0, stream>>>(Wiou, Wf, bth, btl);
  gemm_split_kernel<<<4096, 256, 65536, stream>>>(inputs, bth, btl, biou, bf_, xiou, xf);
  scan_kernel<<<256, 256, 143872, stream>>>(xiou, xf, parents, Uiou, Uf,
                                            hsum, fcsum, hx, cnt, out);
}

// Round 2
// 4512.107 us; speedup vs baseline: 1.2068x; 1.2068x over previous
//
#include <hip/hip_runtime.h>
#include <hip/hip_bf16.h>
#include <cstdint>
#include <cstddef>

#define DI __device__ __forceinline__
#define RLX __ATOMIC_RELAXED
#define AGT __HIP_MEMORY_SCOPE_AGENT

typedef __attribute__((ext_vector_type(8))) short          bf16x8;
typedef __attribute__((ext_vector_type(8))) unsigned short u16x8;
typedef __attribute__((ext_vector_type(4))) float          f32x4;

// ---- problem constants ----
constexpr int Sv = 512, Bv = 128, Dv = 512, Hv = 256;
constexpr int Mv = Sv * Bv;   // 65536 GEMM rows

// ---- workspace layout (bytes) ----
constexpr size_t SZ_HSUM   = (size_t)Bv * (Sv + 1) * Hv * 4;   // 67,239,936
constexpr size_t OFF_HSUM  = 0;
constexpr size_t OFF_FCSUM = SZ_HSUM;
constexpr size_t OFF_FLAGS = 2 * SZ_HSUM;                      // 32 groups * 64 ints = 8 KB
constexpr size_t MEMSET_BYTES = 2 * SZ_HSUM + 8192;
constexpr size_t OFF_HX    = MEMSET_BYTES;                     // 2*128*256*4 = 262144
constexpr size_t OFF_XIOU  = OFF_HX + 262144;
constexpr size_t OFF_XF    = OFF_XIOU + (size_t)Mv * 768 * 4;  // 201,326,592
constexpr size_t OFF_BTH   = OFF_XF + (size_t)Mv * 256 * 4;    //  67,108,864
constexpr size_t OFF_BTL   = OFF_BTH + (size_t)1024 * 512 * 2; //   1,048,576

DI unsigned short f2bf(float x) {  // RNE float->bf16 bits
  union { float f; uint32_t u; } v; v.f = x;
  uint32_t r = v.u + 0x7fffu + ((v.u >> 16) & 1u);
  return (unsigned short)(r >> 16);
}
DI float bf2f(unsigned short b) {
  union { uint32_t u; float f; } v; v.u = ((uint32_t)b) << 16; return v.f;
}
DI float sigm(float x) { return 1.0f / (1.0f + __expf(-x)); }

// =============== W transpose + bf16 hi/lo split: BT[n][k], n in [0,1024) ===============
__global__ void cvt_w_kernel(const float* __restrict__ Wiou, const float* __restrict__ Wf,
                             unsigned short* __restrict__ bth, unsigned short* __restrict__ btl)
{
  int idx = blockIdx.x * 256 + threadIdx.x;  // 1024*512 threads
  int n = idx >> 9, k = idx & 511;
  float v = (n < 768) ? Wiou[(size_t)k * 768 + n] : Wf[(size_t)k * 256 + (n - 768)];
  unsigned short h = f2bf(v);
  bth[idx] = h;
  btl[idx] = f2bf(v - bf2f(h));
}

// =============== split-bf16 GEMM: x = inputs @ [W_iou|W_f] + bias (3-term, fp32-accurate) ===============
#define GLD_LDS16(gp, lp) __builtin_amdgcn_global_load_lds( \
    (const __attribute__((address_space(1))) unsigned int*)(gp), \
    (__attribute__((address_space(3))) unsigned int*)(lp), 16, 0, 0)

__global__ __launch_bounds__(256, 2)
void gemm_split_kernel(const float* __restrict__ A,
                       const unsigned short* __restrict__ BTh,
                       const unsigned short* __restrict__ BTl,
                       const float* __restrict__ biou, const float* __restrict__ bfv,
                       float* __restrict__ xiou, float* __restrict__ xf)
{
  extern __shared__ char lds[];
  unsigned short* As = (unsigned short*)lds;             // [2][128][64] bf16
  unsigned short* Bs = (unsigned short*)(lds + 32768);   // [2][128][64] bf16

  const int bid = blockIdx.x;
  const int ntile = bid & 7, mtile = bid >> 3;
  const int m0 = mtile * 128, n0 = ntile * 128;
  const int tid = threadIdx.x;
  const int lane = tid & 63, w = tid >> 6;
  const int wr = w >> 1, wc = w & 1;

  f32x4 acc[4][4];
  #pragma unroll
  for (int i = 0; i < 4; i++)
    #pragma unroll
    for (int jj = 0; jj < 4; jj++) acc[i][jj] = f32x4{0.f, 0.f, 0.f, 0.f};

  const int arow = tid >> 1, ahalf = tid & 1;
  float areg[32];

  auto issueA = [&](int kk0) {
    const float* g = A + (size_t)(m0 + arow) * 512 + kk0 + ahalf * 32;
    #pragma unroll
    for (int i = 0; i < 8; i++) {
      f32x4 v = ((const f32x4*)g)[i];
      areg[i * 4 + 0] = v[0]; areg[i * 4 + 1] = v[1];
      areg[i * 4 + 2] = v[2]; areg[i * 4 + 3] = v[3];
    }
  };
  auto writeA = [&](int buf, int low) {
    unsigned short* dst = As + buf * 8192 + arow * 64 + ahalf * 32;
    #pragma unroll
    for (int i = 0; i < 4; i++) {
      u16x8 o;
      #pragma unroll
      for (int jj = 0; jj < 8; jj++) {
        float x = areg[i * 8 + jj];
        unsigned short h = f2bf(x);
        o[jj] = low ? f2bf(x - bf2f(h)) : h;
      }
      *(u16x8*)(dst + i * 8) = o;
    }
  };
  auto stageB = [&](int buf, const unsigned short* Bbase, int kk0) {
    #pragma unroll
    for (int q = 0; q < 4; q++) {
      int cidx = q * 256 + tid;
      int row = cidx >> 3, blk = cidx & 7;
      const unsigned short* g = Bbase + (size_t)(n0 + row) * 512 + kk0 + blk * 8;
      unsigned short* l = Bs + buf * 8192 + cidx * 8;
      GLD_LDS16(g, l);
    }
  };
  auto alow = [](int t) { return ((t >> 3) == 1) ? 1 : 0; };

  issueA(0);
  stageB(0, BTh, 0);
  asm volatile("s_waitcnt vmcnt(0)" ::: "memory");
  writeA(0, alow(0));
  __syncthreads();

  for (int t = 0; t < 24; ++t) {
    const int buf = t & 1;
    if (t < 23) {
      const int tn = t + 1;
      issueA((tn & 7) * 64);
      stageB(buf ^ 1, (tn < 16) ? BTh : BTl, (tn & 7) * 64);
    }
    #pragma unroll
    for (int kk = 0; kk < 64; kk += 32) {
      const int k8 = (lane >> 4) * 8;
      bf16x8 af[4], bfrag[4];
      #pragma unroll
      for (int mi = 0; mi < 4; ++mi)
        af[mi] = *(const bf16x8*)(As + buf * 8192 + (size_t)(wr * 64 + mi * 16 + (lane & 15)) * 64 + kk + k8);
      #pragma unroll
      for (int ni = 0; ni < 4; ++ni)
        bfrag[ni] = *(const bf16x8*)(Bs + buf * 8192 + (size_t)(wc * 64 + ni * 16 + (lane & 15)) * 64 + kk + k8);
      #pragma unroll
      for (int mi = 0; mi < 4; ++mi)
        #pragma unroll
        for (int ni = 0; ni < 4; ++ni)
          acc[mi][ni] = __builtin_amdgcn_mfma_f32_16x16x32_bf16(af[mi], bfrag[ni], acc[mi][ni], 0, 0, 0);
    }
    if (t < 23) {
      asm volatile("s_waitcnt vmcnt(0)" ::: "memory");
      writeA(buf ^ 1, alow(t + 1));
    }
    __syncthreads();
  }

  const bool isiou = (n0 < 768);  // block-uniform
  #pragma unroll
  for (int ni = 0; ni < 4; ++ni) {
    int coln = n0 + wc * 64 + ni * 16 + (lane & 15);
    float bv = isiou ? biou[coln] : bfv[coln - 768];
    float* dst = isiou ? (xiou + coln) : (xf + (coln - 768));
    const int ld = isiou ? 768 : 256;
    #pragma unroll
    for (int mi = 0; mi < 4; ++mi)
      #pragma unroll
      for (int r = 0; r < 4; ++r) {
        int rowm = m0 + wr * 64 + mi * 16 + (lane >> 4) * 4 + r;
        dst[(size_t)rowm * ld] = acc[mi][ni][r] + bv;
      }
  }
}

// =============== sequential scan: 32 groups x 4 batches; 8 column-split wgs per group ===============
// One flag-barrier per step; GEMV-f of node s-1 folded into iteration s; private
// inputs (x_iou, parents, fcsum, xf) prefetched during the spin window.
__global__ __launch_bounds__(256, 1)
void scan_kernel(const float* __restrict__ xiou, const float* __restrict__ xf,
                 const int* __restrict__ parents,
                 const float* __restrict__ Uiou, const float* __restrict__ Uf,
                 float* hsum, float* fcsum, float* hx, int* flags,
                 float* __restrict__ out)
{
  extern __shared__ char lds[];
  float* UT   = (float*)lds;                  // [64 m4][128 lc][4] fp32 = 131072 B
  float* htb  = (float*)(lds + 131072);       // [4][256]
  float* hfb  = (float*)(lds + 135168);       // [4][256]
  float* red  = (float*)(lds + 139264);       // [128][2][4]
  float* cbuf = (float*)(lds + 143360);       // [4][32]
  float* fcor = (float*)(lds + 143872);       // [4][32]
  int*   pl   = (int*)(lds + 144384);         // [4]

  const int bid = blockIdx.x;
  const int g = bid & 31, j = bid >> 5;       // all members of group g share bid%8 -> same XCD heuristic
  const int tid = threadIdx.x;
  const int lane = tid & 63, w = tid >> 6;
  const int b0 = g * 4;

  // fill UT: lc = gate*32+hc (gate 0..2 iou, 3 f), layout [m>>2][lc][m&3]
  for (int it = 0; it < 128; ++it) {
    int idx = it * 256 + tid;
    int m = idx >> 7, lc = idx & 127;
    int gate = lc >> 5, hc = lc & 31;
    float v = (gate < 3) ? Uiou[(size_t)m * 768 + gate * 256 + j * 32 + hc]
                         : Uf[(size_t)m * 256 + j * 32 + hc];
    UT[(size_t)(m >> 2) * 512 + lc * 4 + (m & 3)] = v;
  }
  if (tid < 4) pl[tid] = -1;
  __syncthreads();

  // iou GEMV mapping: lc lane-consecutive -> conflict-free b128
  const int ilc = (w & 1) * 64 + lane;
  const int imh = w >> 1;
  const float* iup = UT + ilc * 4;
  // f GEMV mapping
  const int ffc = tid & 31, ffh = (tid >> 5) & 1, fbb = tid >> 6;
  const float* fup = UT + (96 + ffc) * 4;
  // activation mapping (tid<128)
  const int ab = tid >> 5, ahc = tid & 31;
  const int abg = b0 + ab;
  const int ahcol = j * 32 + ahc;

  // prefetch for s=0
  float xg_i = 0.f, xg_o = 0.f, xg_u = 0.f, fct_pre = 0.f;
  int p_act = 0;
  if (tid < 128) {
    size_t xrow = (size_t)abg * 768;
    xg_i = xiou[xrow + ahcol];
    xg_o = xiou[xrow + 256 + ahcol];
    xg_u = xiou[xrow + 512 + ahcol];
    p_act = parents[abg * 512];
    fct_pre = __hip_atomic_load(&fcsum[((size_t)abg * 513) * 256 + ahcol], RLX, AGT);
  }
  int p_f = 0; float xfv = 0.f;

  #pragma unroll 1
  for (int s = 0; s < 512; ++s) {
    // ---- stage htb = hsum[:, s] and hfb = h(s-1) ----
    #pragma unroll
    for (int q = 0; q < 4; ++q) {
      int idx = q * 256 + tid;
      int b = idx >> 8, m = idx & 255;
      htb[b * 256 + m] = __hip_atomic_load(&hsum[((size_t)(b0 + b) * 513 + s) * 256 + m], RLX, AGT);
    }
    if (s > 0) {
      const int sp = (s - 1) & 1;
      #pragma unroll
      for (int q = 0; q < 4; ++q) {
        int idx = q * 256 + tid;
        int b = idx >> 8, m = idx & 255;
        hfb[b * 256 + m] = __hip_atomic_load(&hx[((size_t)sp * 128 + b0 + b) * 256 + m], RLX, AGT);
      }
    }
    __syncthreads();

    // ---- GEMV f for node s-1 (uses hfb, cbuf of s-1) ----
    if (s > 0) {
      float fa = 0.f;
      const float* hb = hfb + fbb * 256;
      #pragma unroll 8
      for (int m4i = 0; m4i < 32; ++m4i) {
        int m4 = ffh * 32 + m4i;
        f32x4 u  = *(const f32x4*)(fup + m4 * 512);
        f32x4 h4 = *(const f32x4*)(hb + m4 * 4);
        fa += u[0]*h4[0] + u[1]*h4[1] + u[2]*h4[2] + u[3]*h4[3];
      }
      fa += __shfl_xor(fa, 32);
      if (ffh == 0) {
        float fgate = sigm(xfv + fa);
        float fcv = fgate * cbuf[fbb * 32 + ffc];
        if (p_f == s) {
          fcor[fbb * 32 + ffc] = fcv;      // consumed this iteration via corr
        } else {
          __hip_atomic_fetch_add(&fcsum[((size_t)(b0 + fbb) * 513 + p_f) * 256 + j * 32 + ffc],
                                 fcv, RLX, AGT);
        }
        if (ffc == 0) pl[fbb] = p_f;
      }
    }

    // ---- GEMV iou for step s ----
    {
      f32x4 a = {0.f, 0.f, 0.f, 0.f};
      #pragma unroll 8
      for (int m4i = 0; m4i < 32; ++m4i) {
        int m4 = imh * 32 + m4i;
        f32x4 u = *(const f32x4*)(iup + m4 * 512);
        const float* hb2 = htb + m4 * 4;
        f32x4 h0 = *(const f32x4*)(hb2);
        f32x4 h1 = *(const f32x4*)(hb2 + 256);
        f32x4 h2 = *(const f32x4*)(hb2 + 512);
        f32x4 h3 = *(const f32x4*)(hb2 + 768);
        a[0] += u[0]*h0[0] + u[1]*h0[1] + u[2]*h0[2] + u[3]*h0[3];
        a[1] += u[0]*h1[0] + u[1]*h1[1] + u[2]*h1[2] + u[3]*h1[3];
        a[2] += u[0]*h2[0] + u[1]*h2[1] + u[2]*h2[2] + u[3]*h2[3];
        a[3] += u[0]*h3[0] + u[1]*h3[1] + u[2]*h3[2] + u[3]*h3[3];
      }
      *(f32x4*)(red + ilc * 8 + imh * 4) = a;
    }
    __syncthreads();

    // ---- activations for step s ----
    if (tid < 128) {
      float fct = fct_pre + ((pl[ab] == s) ? fcor[ab * 32 + ahc] : 0.f);
      float gi = xg_i + red[ahc * 8 + ab]        + red[ahc * 8 + 4 + ab];
      float go = xg_o + red[(32 + ahc) * 8 + ab] + red[(32 + ahc) * 8 + 4 + ab];
      float gu = xg_u + red[(64 + ahc) * 8 + ab] + red[(64 + ahc) * 8 + 4 + ab];
      float iv = sigm(gi), ov = sigm(go), uv = tanhf(gu);
      float c = iv * uv + fct;
      float h = ov * tanhf(c);
      cbuf[ab * 32 + ahc] = c;
      out[((size_t)s * 128 + abg) * 256 + ahcol] = h;
      if (s == 511) out[(size_t)512 * 128 * 256 + (size_t)abg * 256 + ahcol] = h;
      if (s < 511) {
        __hip_atomic_fetch_add(&hsum[((size_t)abg * 513 + p_act) * 256 + ahcol], h, RLX, AGT);
        __hip_atomic_store(&hx[((size_t)(s & 1) * 128 + abg) * 256 + ahcol], h, RLX, AGT);
      }
    }

    // ---- drain, prefetch s+1 (overlaps spin), flag barrier ----
    if (s < 511) {
      asm volatile("s_waitcnt vmcnt(0)" ::: "memory");
      __syncthreads();   // all waves drained -> all step-s writes visible
      const int sn = s + 1;
      if (w == 0 && lane == 0)
        __hip_atomic_store(&flags[g * 64 + j], sn, RLX, AGT);
      if (tid < 128) {
        size_t xrow = ((size_t)sn * 128 + abg) * 768;
        xg_i = xiou[xrow + ahcol];
        xg_o = xiou[xrow + 256 + ahcol];
        xg_u = xiou[xrow + 512 + ahcol];
        p_act = parents[abg * 512 + sn];
        fct_pre = __hip_atomic_load(&fcsum[((size_t)abg * 513 + sn) * 256 + ahcol], RLX, AGT);
      }
      p_f = parents[(b0 + fbb) * 512 + s];                       // node s's parent
      xfv = xf[((size_t)p_f * 128 + (b0 + fbb)) * 256 + j * 32 + ffc];
      if (w == 0) {
        for (;;) {
          int v = __hip_atomic_load(&flags[g * 64 + (lane & 7)], RLX, AGT);
          if (__all(v >= sn)) break;
        }
      }
      __syncthreads();
    }
  }
}

extern "C" void kernel_launch(void* const* d_in, const int* in_sizes, int n_in,
                              void* d_out, int out_size, void* d_ws, size_t ws_size,
                              hipStream_t stream)
{
  (void)in_sizes; (void)n_in; (void)out_size; (void)ws_size;
  const float* inputs  = (const float*)d_in[0];
  const int*   parents = (const int*)d_in[1];
  const float* Wiou    = (const float*)d_in[2];
  const float* biou    = (const float*)d_in[3];
  const float* Uiou    = (const float*)d_in[4];
  const float* Wf      = (const float*)d_in[5];
  const float* bf_     = (const float*)d_in[6];
  const float* Uf      = (const float*)d_in[7];
  float* out = (float*)d_out;
  char* ws = (char*)d_ws;

  float* hsum  = (float*)(ws + OFF_HSUM);
  float* fcsum = (float*)(ws + OFF_FCSUM);
  int*   flags = (int*)(ws + OFF_FLAGS);
  float* hx    = (float*)(ws + OFF_HX);
  float* xiou  = (float*)(ws + OFF_XIOU);
  float* xf    = (float*)(ws + OFF_XF);
  unsigned short* bth = (unsigned short*)(ws + OFF_BTH);
  unsigned short* btl = (unsigned short*)(ws + OFF_BTL);

  hipMemsetAsync(ws, 0, MEMSET_BYTES, stream);

  hipFuncSetAttribute((const void*)gemm_split_kernel,
                      hipFuncAttributeMaxDynamicSharedMemorySize, 65536);
  hipFuncSetAttribute((const void*)scan_kernel,
                      hipFuncAttributeMaxDynamicSharedMemorySize, 147456);

  cvt_w_kernel<<<2048, 256, 0, stream>>>(Wiou, Wf, bth, btl);
  gemm_split_kernel<<<4096, 256, 65536, stream>>>(inputs, bth, btl, biou, bf_, xiou, xf);
  scan_kernel<<<256, 256, 144400, stream>>>(xiou, xf, parents, Uiou, Uf,
                                            hsum, fcsum, hx, flags, out);
}

// Round 4
// 3232.367 us; speedup vs baseline: 1.6846x; 1.3959x over previous
//
#include <hip/hip_runtime.h>
#include <hip/hip_bf16.h>
#include <cstdint>
#include <cstddef>

#define DI __device__ __forceinline__
#define RLX __ATOMIC_RELAXED
#define AGT __HIP_MEMORY_SCOPE_AGENT

typedef __attribute__((ext_vector_type(8))) short          bf16x8;
typedef __attribute__((ext_vector_type(8))) unsigned short u16x8;
typedef __attribute__((ext_vector_type(4))) float          f32x4;

// ---- problem constants ----
constexpr int Sv = 512, Bv = 128, Dv = 512, Hv = 256;

// ---- workspace layout (bytes) ----
constexpr size_t SZ_FCSUM  = (size_t)128 * 513 * 256 * 4;      // 67,239,936
constexpr size_t OFF_FCSUM = 0;
constexpr size_t OFF_FLAGS = SZ_FCSUM;                          // 8 KB flags
constexpr size_t MEMSET_BYTES = SZ_FCSUM + 8192;
constexpr size_t OFF_HX    = MEMSET_BYTES;                      // 2*8*16*256*4 = 262,144
constexpr size_t OFF_GSUM  = OFF_HX + 262144;                   // 128*513*768*4 = 201,719,808
constexpr size_t OFF_XF    = OFF_GSUM + (size_t)128 * 513 * 768 * 4;  // 67,108,864
constexpr size_t OFF_BTH   = OFF_XF + (size_t)512 * 128 * 256 * 4;    // 1,048,576
constexpr size_t OFF_BTL   = OFF_BTH + (size_t)1024 * 512 * 2;        // 1,048,576
constexpr size_t OFF_UH    = OFF_BTL + (size_t)1024 * 512 * 2;        //   524,288
constexpr size_t OFF_UL    = OFF_UH + (size_t)1024 * 256 * 2;         //   524,288
// total ~339.5 MB

DI unsigned short f2bf(float x) {  // RNE float->bf16 bits
  union { float f; uint32_t u; } v; v.f = x;
  uint32_t r = v.u + 0x7fffu + ((v.u >> 16) & 1u);
  return (unsigned short)(r >> 16);
}
DI float bf2f(unsigned short b) {
  union { uint32_t u; float f; } v; v.u = ((uint32_t)b) << 16; return v.f;
}
DI float sigm(float x) { return 1.0f / (1.0f + __expf(-x)); }

// =============== W transpose + bf16 hi/lo split: BT[n][k], n in [0,1024) ===============
__global__ void cvt_w_kernel(const float* __restrict__ Wiou, const float* __restrict__ Wf,
                             unsigned short* __restrict__ bth, unsigned short* __restrict__ btl)
{
  int idx = blockIdx.x * 256 + threadIdx.x;  // 1024*512
  int n = idx >> 9, k = idx & 511;
  float v = (n < 768) ? Wiou[(size_t)k * 768 + n] : Wf[(size_t)k * 256 + (n - 768)];
  unsigned short h = f2bf(v);
  bth[idx] = h;
  btl[idx] = f2bf(v - bf2f(h));
}

// =============== U -> bf16 hi/lo, [col][k] layout for B-fragment loads ===============
__global__ void cvt_u_kernel(const float* __restrict__ Uiou, const float* __restrict__ Uf,
                             unsigned short* __restrict__ uh, unsigned short* __restrict__ ul)
{
  int idx = blockIdx.x * 256 + threadIdx.x;  // 1024 cols * 256 k
  int col = idx >> 8, k = idx & 255;
  float v = (col < 768) ? Uiou[(size_t)k * 768 + col] : Uf[(size_t)k * 256 + (col - 768)];
  unsigned short h = f2bf(v);
  uh[idx] = h;
  ul[idx] = f2bf(v - bf2f(h));
}

// =============== split-bf16 GEMM: gsum[b][s][iou] = inputs @ W_iou + b; xf[s][b][.] ===============
#define GLD_LDS16(gp, lp) __builtin_amdgcn_global_load_lds( \
    (const __attribute__((address_space(1))) unsigned int*)(gp), \
    (__attribute__((address_space(3))) unsigned int*)(lp), 16, 0, 0)

__global__ __launch_bounds__(256, 2)
void gemm_split_kernel(const float* __restrict__ A,
                       const unsigned short* __restrict__ BTh,
                       const unsigned short* __restrict__ BTl,
                       const float* __restrict__ biou, const float* __restrict__ bfv,
                       float* __restrict__ gsum, float* __restrict__ xf)
{
  extern __shared__ char lds[];
  unsigned short* As = (unsigned short*)lds;             // [2][128][64]
  unsigned short* Bs = (unsigned short*)(lds + 32768);   // [2][128][64]

  const int bid = blockIdx.x;
  const int ntile = bid & 7, mtile = bid >> 3;
  const int m0 = mtile * 128, n0 = ntile * 128;
  const int tid = threadIdx.x;
  const int lane = tid & 63, w = tid >> 6;
  const int wr = w >> 1, wc = w & 1;

  f32x4 acc[4][4];
  #pragma unroll
  for (int i = 0; i < 4; i++)
    #pragma unroll
    for (int jj = 0; jj < 4; jj++) acc[i][jj] = f32x4{0.f, 0.f, 0.f, 0.f};

  const int arow = tid >> 1, ahalf = tid & 1;
  float areg[32];

  auto issueA = [&](int kk0) {
    const float* g = A + (size_t)(m0 + arow) * 512 + kk0 + ahalf * 32;
    #pragma unroll
    for (int i = 0; i < 8; i++) {
      f32x4 v = ((const f32x4*)g)[i];
      areg[i * 4 + 0] = v[0]; areg[i * 4 + 1] = v[1];
      areg[i * 4 + 2] = v[2]; areg[i * 4 + 3] = v[3];
    }
  };
  auto writeA = [&](int buf, int low) {
    unsigned short* dst = As + buf * 8192 + arow * 64 + ahalf * 32;
    #pragma unroll
    for (int i = 0; i < 4; i++) {
      u16x8 o;
      #pragma unroll
      for (int jj = 0; jj < 8; jj++) {
        float x = areg[i * 8 + jj];
        unsigned short h = f2bf(x);
        o[jj] = low ? f2bf(x - bf2f(h)) : h;
      }
      *(u16x8*)(dst + i * 8) = o;
    }
  };
  auto stageB = [&](int buf, const unsigned short* Bbase, int kk0) {
    #pragma unroll
    for (int q = 0; q < 4; q++) {
      int cidx = q * 256 + tid;
      int row = cidx >> 3, blk = cidx & 7;
      const unsigned short* g = Bbase + (size_t)(n0 + row) * 512 + kk0 + blk * 8;
      unsigned short* l = Bs + buf * 8192 + cidx * 8;
      GLD_LDS16(g, l);
    }
  };
  auto alow = [](int t) { return ((t >> 3) == 1) ? 1 : 0; };

  issueA(0);
  stageB(0, BTh, 0);
  asm volatile("s_waitcnt vmcnt(0)" ::: "memory");
  writeA(0, alow(0));
  __syncthreads();

  for (int t = 0; t < 24; ++t) {
    const int buf = t & 1;
    if (t < 23) {
      const int tn = t + 1;
      issueA((tn & 7) * 64);
      stageB(buf ^ 1, (tn < 16) ? BTh : BTl, (tn & 7) * 64);
    }
    #pragma unroll
    for (int kk = 0; kk < 64; kk += 32) {
      const int k8 = (lane >> 4) * 8;
      bf16x8 af[4], bfrag[4];
      #pragma unroll
      for (int mi = 0; mi < 4; ++mi)
        af[mi] = *(const bf16x8*)(As + buf * 8192 + (size_t)(wr * 64 + mi * 16 + (lane & 15)) * 64 + kk + k8);
      #pragma unroll
      for (int ni = 0; ni < 4; ++ni)
        bfrag[ni] = *(const bf16x8*)(Bs + buf * 8192 + (size_t)(wc * 64 + ni * 16 + (lane & 15)) * 64 + kk + k8);
      #pragma unroll
      for (int mi = 0; mi < 4; ++mi)
        #pragma unroll
        for (int ni = 0; ni < 4; ++ni)
          acc[mi][ni] = __builtin_amdgcn_mfma_f32_16x16x32_bf16(af[mi], bfrag[ni], acc[mi][ni], 0, 0, 0);
    }
    if (t < 23) {
      asm volatile("s_waitcnt vmcnt(0)" ::: "memory");
      writeA(buf ^ 1, alow(t + 1));
    }
    __syncthreads();
  }

  const bool isiou = (n0 < 768);  // block-uniform
  const int s_ = mtile;           // one s per m-tile (128 rows = all batches)
  #pragma unroll
  for (int ni = 0; ni < 4; ++ni) {
    int coln = n0 + wc * 64 + ni * 16 + (lane & 15);
    float bv = isiou ? biou[coln] : bfv[coln - 768];
    #pragma unroll
    for (int mi = 0; mi < 4; ++mi)
      #pragma unroll
      for (int r = 0; r < 4; ++r) {
        int bg = wr * 64 + mi * 16 + (lane >> 4) * 4 + r;
        float v = acc[mi][ni][r] + bv;
        if (isiou) gsum[((size_t)bg * 513 + s_) * 768 + coln] = v;
        else       xf[((size_t)s_ * 128 + bg) * 256 + (coln - 768)] = v;
      }
  }
}

// =============== scan: 8 groups x 16 batches; 8 col-split wgs (32 h-cols, 4 gates) ===============
// U in registers (3-term bf16 split); per step ONE MFMA block over all gates;
// child contributions scattered into gate-space gsum/fcsum (wg-private).
// ALL cross-wg data (hx) published/read with agent-scope atomics (L3 coherence point).
__global__ __launch_bounds__(512, 1)
void scan_kernel(const unsigned short* __restrict__ ubh, const unsigned short* __restrict__ ubl,
                 const float* __restrict__ xf, const int* __restrict__ parents,
                 float* gsum, float* fcsum, unsigned* hx, int* flags,
                 float* __restrict__ out)
{
  __shared__ __align__(16) unsigned short AH[8 * 64 * 8];   // A-frags hi: [kc][lane][8]
  __shared__ __align__(16) unsigned short AL[8 * 64 * 8];   // A-frags lo
  __shared__ float gcor[16 * 96];
  __shared__ float fcor[16 * 32];
  __shared__ float cbuf[16 * 32];
  __shared__ int   pbuf[2][16];
  __shared__ int   pl[16];

  const int bid = blockIdx.x;
  const int g = bid >> 3, j = bid & 7;
  const int tid = threadIdx.x;
  const int lane = tid & 63, w = tid >> 6;
  const int gb = g * 16;

  // ---- B-frag preload: wave w -> gate w>>1, col-half w&1 (16 cols) ----
  const int colb = (w >> 1) * 256 + j * 32 + (w & 1) * 16;
  const int bcol = colb + (lane & 15);
  const int bk8 = (lane >> 4) * 8;
  bf16x8 BH[8], BL[8];
  #pragma unroll
  for (int kc = 0; kc < 8; ++kc) {
    BH[kc] = *(const bf16x8*)(ubh + (size_t)bcol * 256 + kc * 32 + bk8);
    BL[kc] = *(const bf16x8*)(ubl + (size_t)bcol * 256 + kc * 32 + bk8);
  }

  // staging ids: thread -> (kc, lane-slot) -> (batch, k0)
  const int skc = tid >> 6, sl = tid & 63;
  const int sb = sl & 15, sk0 = skc * 32 + (sl >> 4) * 8;
  // activation ids
  const int ab = tid >> 5, ahc = tid & 31;
  const int abs_b = gb + ab, acol = j * 32 + ahc;
  // f ids
  const bool isf = (w >= 6);
  const int fr0 = (lane >> 4) * 4;
  const int fcl = (w & 1) * 16 + (lane & 15);

  if (tid < 16) { pbuf[0][tid] = parents[(gb + tid) * 512]; pl[tid] = -1; }

  float pre_i, pre_o, pre_u, fct_pre;
  {
    size_t gi0 = ((size_t)abs_b * 513) * 768 + acol;
    pre_i = __hip_atomic_load(&gsum[gi0], RLX, AGT);
    pre_o = __hip_atomic_load(&gsum[gi0 + 256], RLX, AGT);
    pre_u = __hip_atomic_load(&gsum[gi0 + 512], RLX, AGT);
    fct_pre = __hip_atomic_load(&fcsum[((size_t)abs_b * 513) * 256 + acol], RLX, AGT);
  }
  float xfv[4] = {0.f, 0.f, 0.f, 0.f};
  __syncthreads();

  #pragma unroll 1
  for (int s = 0; s < 512; ++s) {
    // ---- stage h(s-1): packed (hi<<16|lo) u32 -> AH/AL frag layout ----
    if (s > 0) {
      const unsigned* src = hx + ((size_t)((s - 1) & 1) * 8 + g) * 4096 + sb * 256 + sk0;
      unsigned vv[8];
      #pragma unroll
      for (int q = 0; q < 8; ++q) vv[q] = __hip_atomic_load(src + q, RLX, AGT);
      u16x8 hiv, lov;
      #pragma unroll
      for (int q = 0; q < 8; ++q) {
        hiv[q] = (unsigned short)(vv[q] >> 16);
        lov[q] = (unsigned short)(vv[q] & 0xffffu);
      }
      *(u16x8*)(AH + skc * 512 + sl * 8) = hiv;
      *(u16x8*)(AL + skc * 512 + sl * 8) = lov;
    }
    __syncthreads();

    // ---- phase B: h(s-1) @ U (all 4 gates, 3-term split), scatter ----
    if (s > 0) {
      f32x4 acc = {0.f, 0.f, 0.f, 0.f};
      #pragma unroll
      for (int kc = 0; kc < 8; ++kc) {
        bf16x8 ah = *(const bf16x8*)(AH + kc * 512 + lane * 8);
        bf16x8 al = *(const bf16x8*)(AL + kc * 512 + lane * 8);
        acc = __builtin_amdgcn_mfma_f32_16x16x32_bf16(ah, BH[kc], acc, 0, 0, 0);
        acc = __builtin_amdgcn_mfma_f32_16x16x32_bf16(al, BH[kc], acc, 0, 0, 0);
        acc = __builtin_amdgcn_mfma_f32_16x16x32_bf16(ah, BL[kc], acc, 0, 0, 0);
      }
      if (!isf) {
        const int colg = colb + (lane & 15);
        const int colL = (w >> 1) * 32 + (w & 1) * 16 + (lane & 15);
        #pragma unroll
        for (int r = 0; r < 4; ++r) {
          int rb = fr0 + r;
          int p = pbuf[(s - 1) & 1][rb];
          if (p == s) gcor[rb * 96 + colL] = acc[r];
          else __hip_atomic_fetch_add(&gsum[((size_t)(gb + rb) * 513 + p) * 768 + colg],
                                      acc[r], RLX, AGT);
        }
      } else {
        #pragma unroll
        for (int r = 0; r < 4; ++r) {
          int rb = fr0 + r;
          int p = pbuf[(s - 1) & 1][rb];
          float fg = sigm(xfv[r] + acc[r]);
          float fc = fg * cbuf[rb * 32 + fcl];
          if (p == s) fcor[rb * 32 + fcl] = fc;
          else __hip_atomic_fetch_add(&fcsum[((size_t)(gb + rb) * 513 + p) * 256 + j * 32 + fcl],
                                      fc, RLX, AGT);
        }
        if (w == 6 && (lane & 15) == 0) {
          #pragma unroll
          for (int r = 0; r < 4; ++r) pl[fr0 + r] = pbuf[(s - 1) & 1][fr0 + r];
        }
      }
      // NOTE: no vmcnt drain here — global scatters only need to complete before
      // the epilogue drain (which precedes the row-(s+1) prefetch). gcor/fcor/pl
      // are LDS, covered by the barrier below.
    }
    __syncthreads();

    // ---- activation for node s (all 512 threads: 16 b x 32 hc) ----
    {
      bool corr = (pl[ab] == s);
      float gi = pre_i + (corr ? gcor[ab * 96 + ahc] : 0.f);
      float go = pre_o + (corr ? gcor[ab * 96 + 32 + ahc] : 0.f);
      float gu = pre_u + (corr ? gcor[ab * 96 + 64 + ahc] : 0.f);
      float fct = fct_pre + (corr ? fcor[ab * 32 + ahc] : 0.f);
      float c = sigm(gi) * tanhf(gu) + fct;
      float h = sigm(go) * tanhf(c);
      cbuf[ab * 32 + ahc] = c;
      out[((size_t)s * 128 + abs_b) * 256 + acol] = h;
      if (s == 511) out[(size_t)512 * 128 * 256 + (size_t)abs_b * 256 + acol] = h;
      else {
        unsigned short hh = f2bf(h);
        unsigned short hl = f2bf(h - bf2f(hh));
        unsigned packed = ((unsigned)hh << 16) | hl;
        __hip_atomic_store(&hx[((size_t)(s & 1) * 8 + g) * 4096 + ab * 256 + acol],
                           packed, RLX, AGT);   // agent scope: visible at L3 to peer XCDs
      }
    }

    // ---- drain, flag, prefetch s+1 (overlaps spin), spin ----
    if (s < 511) {
      asm volatile("s_waitcnt vmcnt(0)" ::: "memory");
      __syncthreads();  // all waves drained -> h(s) + all scatters fully published
      const int sn = s + 1;
      if (tid == 0) __hip_atomic_store(&flags[g * 64 + j], sn, RLX, AGT);
      {
        size_t gi1 = ((size_t)abs_b * 513 + sn) * 768 + acol;
        pre_i = __hip_atomic_load(&gsum[gi1], RLX, AGT);
        pre_o = __hip_atomic_load(&gsum[gi1 + 256], RLX, AGT);
        pre_u = __hip_atomic_load(&gsum[gi1 + 512], RLX, AGT);
        fct_pre = __hip_atomic_load(&fcsum[((size_t)abs_b * 513 + sn) * 256 + acol], RLX, AGT);
      }
      if (tid < 16) pbuf[sn & 1][tid] = parents[(gb + tid) * 512 + sn];
      if (isf) {
        #pragma unroll
        for (int r = 0; r < 4; ++r) {
          int p = pbuf[s & 1][fr0 + r];   // parents[.][s], loaded last window
          xfv[r] = (p < 512) ? xf[((size_t)p * 128 + (gb + fr0 + r)) * 256 + j * 32 + fcl] : 0.f;
        }
      }
      if (w == 0) {
        for (;;) {
          int v = __hip_atomic_load(&flags[g * 64 + (lane & 7)], RLX, AGT);
          if (__all(v >= sn)) break;
        }
      }
      __syncthreads();
    }
  }
}

extern "C" void kernel_launch(void* const* d_in, const int* in_sizes, int n_in,
                              void* d_out, int out_size, void* d_ws, size_t ws_size,
                              hipStream_t stream)
{
  (void)in_sizes; (void)n_in; (void)out_size; (void)ws_size;
  const float* inputs  = (const float*)d_in[0];
  const int*   parents = (const int*)d_in[1];
  const float* Wiou    = (const float*)d_in[2];
  const float* biou    = (const float*)d_in[3];
  const float* Uiou    = (const float*)d_in[4];
  const float* Wf      = (const float*)d_in[5];
  const float* bf_     = (const float*)d_in[6];
  const float* Uf      = (const float*)d_in[7];
  float* out = (float*)d_out;
  char* ws = (char*)d_ws;

  float* fcsum = (float*)(ws + OFF_FCSUM);
  int*   flags = (int*)(ws + OFF_FLAGS);
  unsigned* hx = (unsigned*)(ws + OFF_HX);
  float* gsum  = (float*)(ws + OFF_GSUM);
  float* xf    = (float*)(ws + OFF_XF);
  unsigned short* bth = (unsigned short*)(ws + OFF_BTH);
  unsigned short* btl = (unsigned short*)(ws + OFF_BTL);
  unsigned short* uh  = (unsigned short*)(ws + OFF_UH);
  unsigned short* ul  = (unsigned short*)(ws + OFF_UL);

  hipMemsetAsync(ws, 0, MEMSET_BYTES, stream);

  hipFuncSetAttribute((const void*)gemm_split_kernel,
                      hipFuncAttributeMaxDynamicSharedMemorySize, 65536);

  cvt_w_kernel<<<2048, 256, 0, stream>>>(Wiou, Wf, bth, btl);
  cvt_u_kernel<<<1024, 256, 0, stream>>>(Uiou, Uf, uh, ul);
  gemm_split_kernel<<<4096, 256, 65536, stream>>>(inputs, bth, btl, biou, bf_, gsum, xf);
  scan_kernel<<<64, 512, 0, stream>>>(uh, ul, xf, parents, gsum, fcsum, hx, flags, out);
}

// Round 5
// 3095.686 us; speedup vs baseline: 1.7590x; 1.0442x over previous
//
#include <hip/hip_runtime.h>
#include <hip/hip_bf16.h>
#include <cstdint>
#include <cstddef>

#define DI __device__ __forceinline__
#define RLX __ATOMIC_RELAXED
#define AGT __HIP_MEMORY_SCOPE_AGENT
#define WGP __HIP_MEMORY_SCOPE_WORKGROUP

typedef __attribute__((ext_vector_type(8))) short          bf16x8;
typedef __attribute__((ext_vector_type(8))) unsigned short u16x8;
typedef __attribute__((ext_vector_type(4))) float          f32x4;

// ---- problem constants ----
constexpr int Sv = 512, Bv = 128, Dv = 512, Hv = 256;

// ---- workspace layout (bytes) ----
constexpr size_t SZ_FCSUM  = (size_t)128 * 513 * 256 * 4;      // 67,239,936
constexpr size_t OFF_FCSUM = 0;
constexpr size_t OFF_FLAGS = SZ_FCSUM;                          // 8 KB flags
constexpr size_t MEMSET_BYTES = SZ_FCSUM + 8192;
constexpr size_t OFF_HX    = MEMSET_BYTES;                      // 2*8*16*256*4 = 262,144
constexpr size_t OFF_GSUM  = OFF_HX + 262144;                   // 128*513*768*4 = 201,719,808
constexpr size_t OFF_XF    = OFF_GSUM + (size_t)128 * 513 * 768 * 4;  // 67,108,864
constexpr size_t OFF_BTH   = OFF_XF + (size_t)512 * 128 * 256 * 4;    // 1,048,576
constexpr size_t OFF_BTL   = OFF_BTH + (size_t)1024 * 512 * 2;        // 1,048,576
constexpr size_t OFF_UH    = OFF_BTL + (size_t)1024 * 512 * 2;        //   524,288
constexpr size_t OFF_UL    = OFF_UH + (size_t)1024 * 256 * 2;         //   524,288
// total ~339.5 MB

DI unsigned short f2bf(float x) {  // RNE float->bf16 bits
  union { float f; uint32_t u; } v; v.f = x;
  uint32_t r = v.u + 0x7fffu + ((v.u >> 16) & 1u);
  return (unsigned short)(r >> 16);
}
DI float bf2f(unsigned short b) {
  union { uint32_t u; float f; } v; v.u = ((uint32_t)b) << 16; return v.f;
}
DI float sigm(float x) { return 1.0f / (1.0f + __expf(-x)); }

// =============== W transpose + bf16 hi/lo split: BT[n][k], n in [0,1024) ===============
__global__ void cvt_w_kernel(const float* __restrict__ Wiou, const float* __restrict__ Wf,
                             unsigned short* __restrict__ bth, unsigned short* __restrict__ btl)
{
  int idx = blockIdx.x * 256 + threadIdx.x;  // 1024*512
  int n = idx >> 9, k = idx & 511;
  float v = (n < 768) ? Wiou[(size_t)k * 768 + n] : Wf[(size_t)k * 256 + (n - 768)];
  unsigned short h = f2bf(v);
  bth[idx] = h;
  btl[idx] = f2bf(v - bf2f(h));
}

// =============== U -> bf16 hi/lo, [col][k] layout for B-fragment loads ===============
__global__ void cvt_u_kernel(const float* __restrict__ Uiou, const float* __restrict__ Uf,
                             unsigned short* __restrict__ uh, unsigned short* __restrict__ ul)
{
  int idx = blockIdx.x * 256 + threadIdx.x;  // 1024 cols * 256 k
  int col = idx >> 8, k = idx & 255;
  float v = (col < 768) ? Uiou[(size_t)k * 768 + col] : Uf[(size_t)k * 256 + (col - 768)];
  unsigned short h = f2bf(v);
  uh[idx] = h;
  ul[idx] = f2bf(v - bf2f(h));
}

// =============== split-bf16 GEMM: gsum[b][s][iou] = inputs @ W_iou + b; xf[s][b][.] ===============
#define GLD_LDS16(gp, lp) __builtin_amdgcn_global_load_lds( \
    (const __attribute__((address_space(1))) unsigned int*)(gp), \
    (__attribute__((address_space(3))) unsigned int*)(lp), 16, 0, 0)

__global__ __launch_bounds__(256, 2)
void gemm_split_kernel(const float* __restrict__ A,
                       const unsigned short* __restrict__ BTh,
                       const unsigned short* __restrict__ BTl,
                       const float* __restrict__ biou, const float* __restrict__ bfv,
                       float* __restrict__ gsum, float* __restrict__ xf)
{
  extern __shared__ char lds[];
  unsigned short* As = (unsigned short*)lds;             // [2][128][64]
  unsigned short* Bs = (unsigned short*)(lds + 32768);   // [2][128][64]

  const int bid = blockIdx.x;
  const int ntile = bid & 7, mtile = bid >> 3;
  const int m0 = mtile * 128, n0 = ntile * 128;
  const int tid = threadIdx.x;
  const int lane = tid & 63, w = tid >> 6;
  const int wr = w >> 1, wc = w & 1;

  f32x4 acc[4][4];
  #pragma unroll
  for (int i = 0; i < 4; i++)
    #pragma unroll
    for (int jj = 0; jj < 4; jj++) acc[i][jj] = f32x4{0.f, 0.f, 0.f, 0.f};

  const int arow = tid >> 1, ahalf = tid & 1;
  float areg[32];

  auto issueA = [&](int kk0) {
    const float* g = A + (size_t)(m0 + arow) * 512 + kk0 + ahalf * 32;
    #pragma unroll
    for (int i = 0; i < 8; i++) {
      f32x4 v = ((const f32x4*)g)[i];
      areg[i * 4 + 0] = v[0]; areg[i * 4 + 1] = v[1];
      areg[i * 4 + 2] = v[2]; areg[i * 4 + 3] = v[3];
    }
  };
  auto writeA = [&](int buf, int low) {
    unsigned short* dst = As + buf * 8192 + arow * 64 + ahalf * 32;
    #pragma unroll
    for (int i = 0; i < 4; i++) {
      u16x8 o;
      #pragma unroll
      for (int jj = 0; jj < 8; jj++) {
        float x = areg[i * 8 + jj];
        unsigned short h = f2bf(x);
        o[jj] = low ? f2bf(x - bf2f(h)) : h;
      }
      *(u16x8*)(dst + i * 8) = o;
    }
  };
  auto stageB = [&](int buf, const unsigned short* Bbase, int kk0) {
    #pragma unroll
    for (int q = 0; q < 4; q++) {
      int cidx = q * 256 + tid;
      int row = cidx >> 3, blk = cidx & 7;
      const unsigned short* g = Bbase + (size_t)(n0 + row) * 512 + kk0 + blk * 8;
      unsigned short* l = Bs + buf * 8192 + cidx * 8;
      GLD_LDS16(g, l);
    }
  };
  auto alow = [](int t) { return ((t >> 3) == 1) ? 1 : 0; };

  issueA(0);
  stageB(0, BTh, 0);
  asm volatile("s_waitcnt vmcnt(0)" ::: "memory");
  writeA(0, alow(0));
  __syncthreads();

  for (int t = 0; t < 24; ++t) {
    const int buf = t & 1;
    if (t < 23) {
      const int tn = t + 1;
      issueA((tn & 7) * 64);
      stageB(buf ^ 1, (tn < 16) ? BTh : BTl, (tn & 7) * 64);
    }
    #pragma unroll
    for (int kk = 0; kk < 64; kk += 32) {
      const int k8 = (lane >> 4) * 8;
      bf16x8 af[4], bfrag[4];
      #pragma unroll
      for (int mi = 0; mi < 4; ++mi)
        af[mi] = *(const bf16x8*)(As + buf * 8192 + (size_t)(wr * 64 + mi * 16 + (lane & 15)) * 64 + kk + k8);
      #pragma unroll
      for (int ni = 0; ni < 4; ++ni)
        bfrag[ni] = *(const bf16x8*)(Bs + buf * 8192 + (size_t)(wc * 64 + ni * 16 + (lane & 15)) * 64 + kk + k8);
      #pragma unroll
      for (int mi = 0; mi < 4; ++mi)
        #pragma unroll
        for (int ni = 0; ni < 4; ++ni)
          acc[mi][ni] = __builtin_amdgcn_mfma_f32_16x16x32_bf16(af[mi], bfrag[ni], acc[mi][ni], 0, 0, 0);
    }
    if (t < 23) {
      asm volatile("s_waitcnt vmcnt(0)" ::: "memory");
      writeA(buf ^ 1, alow(t + 1));
    }
    __syncthreads();
  }

  const bool isiou = (n0 < 768);  // block-uniform
  const int s_ = mtile;           // one s per m-tile (128 rows = all batches)
  #pragma unroll
  for (int ni = 0; ni < 4; ++ni) {
    int coln = n0 + wc * 64 + ni * 16 + (lane & 15);
    float bv = isiou ? biou[coln] : bfv[coln - 768];
    #pragma unroll
    for (int mi = 0; mi < 4; ++mi)
      #pragma unroll
      for (int r = 0; r < 4; ++r) {
        int bg = wr * 64 + mi * 16 + (lane >> 4) * 4 + r;
        float v = acc[mi][ni][r] + bv;
        if (isiou) gsum[((size_t)bg * 513 + s_) * 768 + coln] = v;
        else       xf[((size_t)s_ * 128 + bg) * 256 + (coln - 768)] = v;
      }
  }
}

// =============== scan: 8 groups x 16 batches; 8 col-split wgs (32 h-cols, 4 gates) ===============
// gsum/fcsum/xf are WG-PRIVATE (only wg (g,j) touches cols j*32 of group g's rows):
// scatters use WORKGROUP-scope atomics (L2-executed), prefetches are plain loads.
// Only hx + flags are cross-wg -> agent scope. Group co-located on one XCD via
// bid mapping (members share bid%8 under round-robin dispatch).
__global__ __launch_bounds__(512, 1)
void scan_kernel(const unsigned short* __restrict__ ubh, const unsigned short* __restrict__ ubl,
                 const float* __restrict__ xf, const int* __restrict__ parents,
                 float* gsum, float* fcsum, unsigned* hx, int* flags,
                 float* __restrict__ out)
{
  __shared__ __align__(16) unsigned short AH[8 * 64 * 8];   // A-frags hi: [kc][lane][8]
  __shared__ __align__(16) unsigned short AL[8 * 64 * 8];   // A-frags lo
  __shared__ float gcor[16 * 96];
  __shared__ float fcor[16 * 32];
  __shared__ float cbuf[16 * 32];
  __shared__ int   pbuf[2][16];
  __shared__ int   pl[16];

  const int bid = blockIdx.x;
  const int g = bid & 7, j = bid >> 3;   // group members share bid%8 -> same XCD (heuristic)
  const int tid = threadIdx.x;
  const int lane = tid & 63, w = tid >> 6;
  const int gb = g * 16;

  // ---- B-frag preload: wave w -> gate w>>1, col-half w&1 (16 cols) ----
  const int colb = (w >> 1) * 256 + j * 32 + (w & 1) * 16;
  const int bcol = colb + (lane & 15);
  const int bk8 = (lane >> 4) * 8;
  bf16x8 BH[8], BL[8];
  #pragma unroll
  for (int kc = 0; kc < 8; ++kc) {
    BH[kc] = *(const bf16x8*)(ubh + (size_t)bcol * 256 + kc * 32 + bk8);
    BL[kc] = *(const bf16x8*)(ubl + (size_t)bcol * 256 + kc * 32 + bk8);
  }

  // staging ids: thread -> (kc, lane-slot) -> (batch, k0)
  const int skc = tid >> 6, sl = tid & 63;
  const int sb = sl & 15, sk0 = skc * 32 + (sl >> 4) * 8;
  // activation ids
  const int ab = tid >> 5, ahc = tid & 31;
  const int abs_b = gb + ab, acol = j * 32 + ahc;
  // f ids
  const bool isf = (w >= 6);
  const int fr0 = (lane >> 4) * 4;
  const int fcl = (w & 1) * 16 + (lane & 15);

  if (tid < 16) { pbuf[0][tid] = parents[(gb + tid) * 512]; pl[tid] = -1; }

  float pre_i, pre_o, pre_u, fct_pre;
  {
    size_t gi0 = ((size_t)abs_b * 513) * 768 + acol;
    pre_i = gsum[gi0];
    pre_o = gsum[gi0 + 256];
    pre_u = gsum[gi0 + 512];
    fct_pre = fcsum[((size_t)abs_b * 513) * 256 + acol];
  }
  float xfv[4] = {0.f, 0.f, 0.f, 0.f};
  __syncthreads();

  #pragma unroll 1
  for (int s = 0; s < 512; ++s) {
    // ---- stage h(s-1): packed (hi<<16|lo) u32 -> AH/AL frag layout (cross-wg: agent) ----
    if (s > 0) {
      const unsigned* src = hx + ((size_t)((s - 1) & 1) * 8 + g) * 4096 + sb * 256 + sk0;
      unsigned vv[8];
      #pragma unroll
      for (int q = 0; q < 8; ++q) vv[q] = __hip_atomic_load(src + q, RLX, AGT);
      u16x8 hiv, lov;
      #pragma unroll
      for (int q = 0; q < 8; ++q) {
        hiv[q] = (unsigned short)(vv[q] >> 16);
        lov[q] = (unsigned short)(vv[q] & 0xffffu);
      }
      *(u16x8*)(AH + skc * 512 + sl * 8) = hiv;
      *(u16x8*)(AL + skc * 512 + sl * 8) = lov;
    }
    __syncthreads();

    // ---- phase B: h(s-1) @ U (all 4 gates, 3-term split, 3 independent MFMA chains) ----
    if (s > 0) {
      f32x4 a0 = {0.f, 0.f, 0.f, 0.f};
      f32x4 a1 = {0.f, 0.f, 0.f, 0.f};
      f32x4 a2 = {0.f, 0.f, 0.f, 0.f};
      #pragma unroll
      for (int kc = 0; kc < 8; ++kc) {
        bf16x8 ah = *(const bf16x8*)(AH + kc * 512 + lane * 8);
        bf16x8 al = *(const bf16x8*)(AL + kc * 512 + lane * 8);
        a0 = __builtin_amdgcn_mfma_f32_16x16x32_bf16(ah, BH[kc], a0, 0, 0, 0);
        a1 = __builtin_amdgcn_mfma_f32_16x16x32_bf16(al, BH[kc], a1, 0, 0, 0);
        a2 = __builtin_amdgcn_mfma_f32_16x16x32_bf16(ah, BL[kc], a2, 0, 0, 0);
      }
      f32x4 acc = a0 + a1 + a2;
      if (!isf) {
        const int colg = colb + (lane & 15);
        const int colL = (w >> 1) * 32 + (w & 1) * 16 + (lane & 15);
        #pragma unroll
        for (int r = 0; r < 4; ++r) {
          int rb = fr0 + r;
          int p = pbuf[(s - 1) & 1][rb];
          if (p == s) gcor[rb * 96 + colL] = acc[r];
          else __hip_atomic_fetch_add(&gsum[((size_t)(gb + rb) * 513 + p) * 768 + colg],
                                      acc[r], RLX, WGP);   // wg-private: L2 atomic
        }
      } else {
        #pragma unroll
        for (int r = 0; r < 4; ++r) {
          int rb = fr0 + r;
          int p = pbuf[(s - 1) & 1][rb];
          float fg = sigm(xfv[r] + acc[r]);
          float fc = fg * cbuf[rb * 32 + fcl];
          if (p == s) fcor[rb * 32 + fcl] = fc;
          else __hip_atomic_fetch_add(&fcsum[((size_t)(gb + rb) * 513 + p) * 256 + j * 32 + fcl],
                                      fc, RLX, WGP);       // wg-private: L2 atomic
        }
        if (w == 6 && (lane & 15) == 0) {
          #pragma unroll
          for (int r = 0; r < 4; ++r) pl[fr0 + r] = pbuf[(s - 1) & 1][fr0 + r];
        }
      }
    }
    __syncthreads();

    // ---- activation for node s (all 512 threads: 16 b x 32 hc) ----
    {
      bool corr = (pl[ab] == s);
      float gi = pre_i + (corr ? gcor[ab * 96 + ahc] : 0.f);
      float go = pre_o + (corr ? gcor[ab * 96 + 32 + ahc] : 0.f);
      float gu = pre_u + (corr ? gcor[ab * 96 + 64 + ahc] : 0.f);
      float fct = fct_pre + (corr ? fcor[ab * 32 + ahc] : 0.f);
      float c = sigm(gi) * tanhf(gu) + fct;
      float h = sigm(go) * tanhf(c);
      if (s < 511) {
        unsigned short hh = f2bf(h);
        unsigned short hl = f2bf(h - bf2f(hh));
        unsigned packed = ((unsigned)hh << 16) | hl;
        __hip_atomic_store(&hx[((size_t)(s & 1) * 8 + g) * 4096 + ab * 256 + acol],
                           packed, RLX, AGT);   // issue cross-wg publish FIRST
      }
      cbuf[ab * 32 + ahc] = c;
      out[((size_t)s * 128 + abs_b) * 256 + acol] = h;
      if (s == 511) out[(size_t)512 * 128 * 256 + (size_t)abs_b * 256 + acol] = h;
    }

    // ---- drain, flag, prefetch s+1 (overlaps spin), spin ----
    if (s < 511) {
      asm volatile("s_waitcnt vmcnt(0)" ::: "memory");
      __syncthreads();  // all waves drained -> h(s) + all scatters fully published
      const int sn = s + 1;
      if (tid == 0) __hip_atomic_store(&flags[g * 64 + j], sn, RLX, AGT);
      {
        size_t gi1 = ((size_t)abs_b * 513 + sn) * 768 + acol;
        pre_i = gsum[gi1];
        pre_o = gsum[gi1 + 256];
        pre_u = gsum[gi1 + 512];
        fct_pre = fcsum[((size_t)abs_b * 513 + sn) * 256 + acol];
      }
      if (tid < 16) pbuf[sn & 1][tid] = parents[(gb + tid) * 512 + sn];
      if (isf) {
        #pragma unroll
        for (int r = 0; r < 4; ++r) {
          int p = pbuf[s & 1][fr0 + r];   // parents[.][s], loaded last window
          xfv[r] = (p < 512) ? xf[((size_t)p * 128 + (gb + fr0 + r)) * 256 + j * 32 + fcl] : 0.f;
        }
      }
      if (w == 0) {
        for (;;) {
          int v = __hip_atomic_load(&flags[g * 64 + (lane & 7)], RLX, AGT);
          if (__all(v >= sn)) break;
        }
      }
      __syncthreads();
    }
  }
}

extern "C" void kernel_launch(void* const* d_in, const int* in_sizes, int n_in,
                              void* d_out, int out_size, void* d_ws, size_t ws_size,
                              hipStream_t stream)
{
  (void)in_sizes; (void)n_in; (void)out_size; (void)ws_size;
  const float* inputs  = (const float*)d_in[0];
  const int*   parents = (const int*)d_in[1];
  const float* Wiou    = (const float*)d_in[2];
  const float* biou    = (const float*)d_in[3];
  const float* Uiou    = (const float*)d_in[4];
  const float* Wf      = (const float*)d_in[5];
  const float* bf_     = (const float*)d_in[6];
  const float* Uf      = (const float*)d_in[7];
  float* out = (float*)d_out;
  char* ws = (char*)d_ws;

  float* fcsum = (float*)(ws + OFF_FCSUM);
  int*   flags = (int*)(ws + OFF_FLAGS);
  unsigned* hx = (unsigned*)(ws + OFF_HX);
  float* gsum  = (float*)(ws + OFF_GSUM);
  float* xf    = (float*)(ws + OFF_XF);
  unsigned short* bth = (unsigned short*)(ws + OFF_BTH);
  unsigned short* btl = (unsigned short*)(ws + OFF_BTL);
  unsigned short* uh  = (unsigned short*)(ws + OFF_UH);
  unsigned short* ul  = (unsigned short*)(ws + OFF_UL);

  hipMemsetAsync(ws, 0, MEMSET_BYTES, stream);

  hipFuncSetAttribute((const void*)gemm_split_kernel,
                      hipFuncAttributeMaxDynamicSharedMemorySize, 65536);

  cvt_w_kernel<<<2048, 256, 0, stream>>>(Wiou, Wf, bth, btl);
  cvt_u_kernel<<<1024, 256, 0, stream>>>(Uiou, Uf, uh, ul);
  gemm_split_kernel<<<4096, 256, 65536, stream>>>(inputs, bth, btl, biou, bf_, gsum, xf);
  scan_kernel<<<64, 512, 0, stream>>>(uh, ul, xf, parents, gsum, fcsum, hx, flags, out);
}

// Round 7
// 2427.297 us; speedup vs baseline: 2.2434x; 1.2754x over previous
//
#include <hip/hip_runtime.h>
#include <hip/hip_bf16.h>
#include <cstdint>
#include <cstddef>

#define DI __device__ __forceinline__
#define RLX __ATOMIC_RELAXED
#define AGT __HIP_MEMORY_SCOPE_AGENT
#define WGP __HIP_MEMORY_SCOPE_WORKGROUP

typedef __attribute__((ext_vector_type(8))) short          bf16x8;
typedef __attribute__((ext_vector_type(8))) unsigned short u16x8;
typedef __attribute__((ext_vector_type(4))) float          f32x4;

// ---- problem constants ----
constexpr int Sv = 512, Bv = 128, Dv = 512, Hv = 256;

// ---- workspace layout (bytes) ----
constexpr size_t SZ_FCSUM  = (size_t)128 * 513 * 256 * 4;            // 67,239,936 (zeroed)
constexpr size_t OFF_FCSUM = 0;
constexpr size_t OFF_HX    = SZ_FCSUM;                               // poisoned 0xFF
constexpr size_t SZ_HX     = (size_t)511 * 128 * 256 * 4;            // 66,977,792
constexpr size_t OFF_GSUM  = OFF_HX + SZ_HX;
constexpr size_t SZ_GSUM   = (size_t)128 * 513 * 768 * 4;            // 201,719,808
constexpr size_t OFF_XF    = OFF_GSUM + SZ_GSUM;
constexpr size_t SZ_XF     = (size_t)512 * 128 * 256 * 4;            // 67,108,864
constexpr size_t OFF_BTH   = OFF_XF + SZ_XF;
constexpr size_t OFF_BTL   = OFF_BTH + (size_t)1024 * 512 * 2;
constexpr size_t OFF_UH    = OFF_BTL + (size_t)1024 * 512 * 2;
constexpr size_t OFF_UL    = OFF_UH + (size_t)1024 * 256 * 2;
// total ~406 MB

DI unsigned short f2bf(float x) {  // RNE float->bf16 bits
  union { float f; uint32_t u; } v; v.f = x;
  uint32_t r = v.u + 0x7fffu + ((v.u >> 16) & 1u);
  return (unsigned short)(r >> 16);
}
DI float bf2f(unsigned short b) {
  union { uint32_t u; float f; } v; v.u = ((uint32_t)b) << 16; return v.f;
}
DI float sigm(float x) { return 1.0f / (1.0f + __expf(-x)); }
// validity: packed h dword has hh exponent bits[30:23] != 0xFF (|h|<=1 -> exp<=0x7F).
// poison 0xFFFFFFFF fails the test.
DI bool okd(unsigned d) { return (d & 0x7F800000u) != 0x7F800000u; }
DI bool ok64(unsigned long long v) { return okd((unsigned)v) && okd((unsigned)(v >> 32)); }

// =============== W transpose + bf16 hi/lo split: BT[n][k], n in [0,1024) ===============
__global__ void cvt_w_kernel(const float* __restrict__ Wiou, const float* __restrict__ Wf,
                             unsigned short* __restrict__ bth, unsigned short* __restrict__ btl)
{
  int idx = blockIdx.x * 256 + threadIdx.x;  // 1024*512
  int n = idx >> 9, k = idx & 511;
  float v = (n < 768) ? Wiou[(size_t)k * 768 + n] : Wf[(size_t)k * 256 + (n - 768)];
  unsigned short h = f2bf(v);
  bth[idx] = h;
  btl[idx] = f2bf(v - bf2f(h));
}

// =============== U -> bf16 hi/lo, [col][k] layout for B-fragment loads ===============
__global__ void cvt_u_kernel(const float* __restrict__ Uiou, const float* __restrict__ Uf,
                             unsigned short* __restrict__ uh, unsigned short* __restrict__ ul)
{
  int idx = blockIdx.x * 256 + threadIdx.x;  // 1024 cols * 256 k
  int col = idx >> 8, k = idx & 255;
  float v = (col < 768) ? Uiou[(size_t)k * 768 + col] : Uf[(size_t)k * 256 + (col - 768)];
  unsigned short h = f2bf(v);
  uh[idx] = h;
  ul[idx] = f2bf(v - bf2f(h));
}

// =============== split-bf16 GEMM: gsum[b][s][iou] = inputs @ W_iou + b; xf[s][b][.] ===============
#define GLD_LDS16(gp, lp) __builtin_amdgcn_global_load_lds( \
    (const __attribute__((address_space(1))) unsigned int*)(gp), \
    (__attribute__((address_space(3))) unsigned int*)(lp), 16, 0, 0)

__global__ __launch_bounds__(256, 2)
void gemm_split_kernel(const float* __restrict__ A,
                       const unsigned short* __restrict__ BTh,
                       const unsigned short* __restrict__ BTl,
                       const float* __restrict__ biou, const float* __restrict__ bfv,
                       float* __restrict__ gsum, float* __restrict__ xf)
{
  extern __shared__ char lds[];
  unsigned short* As = (unsigned short*)lds;             // [2][128][64]
  unsigned short* Bs = (unsigned short*)(lds + 32768);   // [2][128][64]

  const int bid = blockIdx.x;
  const int ntile = bid & 7, mtile = bid >> 3;
  const int m0 = mtile * 128, n0 = ntile * 128;
  const int tid = threadIdx.x;
  const int lane = tid & 63, w = tid >> 6;
  const int wr = w >> 1, wc = w & 1;

  f32x4 acc[4][4];
  #pragma unroll
  for (int i = 0; i < 4; i++)
    #pragma unroll
    for (int jj = 0; jj < 4; jj++) acc[i][jj] = f32x4{0.f, 0.f, 0.f, 0.f};

  const int arow = tid >> 1, ahalf = tid & 1;
  float areg[32];

  auto issueA = [&](int kk0) {
    const float* g = A + (size_t)(m0 + arow) * 512 + kk0 + ahalf * 32;
    #pragma unroll
    for (int i = 0; i < 8; i++) {
      f32x4 v = ((const f32x4*)g)[i];
      areg[i * 4 + 0] = v[0]; areg[i * 4 + 1] = v[1];
      areg[i * 4 + 2] = v[2]; areg[i * 4 + 3] = v[3];
    }
  };
  auto writeA = [&](int buf, int low) {
    unsigned short* dst = As + buf * 8192 + arow * 64 + ahalf * 32;
    #pragma unroll
    for (int i = 0; i < 4; i++) {
      u16x8 o;
      #pragma unroll
      for (int jj = 0; jj < 8; jj++) {
        float x = areg[i * 8 + jj];
        unsigned short h = f2bf(x);
        o[jj] = low ? f2bf(x - bf2f(h)) : h;
      }
      *(u16x8*)(dst + i * 8) = o;
    }
  };
  auto stageB = [&](int buf, const unsigned short* Bbase, int kk0) {
    #pragma unroll
    for (int q = 0; q < 4; q++) {
      int cidx = q * 256 + tid;
      int row = cidx >> 3, blk = cidx & 7;
      const unsigned short* g = Bbase + (size_t)(n0 + row) * 512 + kk0 + blk * 8;
      unsigned short* l = Bs + buf * 8192 + cidx * 8;
      GLD_LDS16(g, l);
    }
  };
  auto alow = [](int t) { return ((t >> 3) == 1) ? 1 : 0; };

  issueA(0);
  stageB(0, BTh, 0);
  asm volatile("s_waitcnt vmcnt(0)" ::: "memory");
  writeA(0, alow(0));
  __syncthreads();

  for (int t = 0; t < 24; ++t) {
    const int buf = t & 1;
    if (t < 23) {
      const int tn = t + 1;
      issueA((tn & 7) * 64);
      stageB(buf ^ 1, (tn < 16) ? BTh : BTl, (tn & 7) * 64);
    }
    #pragma unroll
    for (int kk = 0; kk < 64; kk += 32) {
      const int k8 = (lane >> 4) * 8;
      bf16x8 af[4], bfrag[4];
      #pragma unroll
      for (int mi = 0; mi < 4; ++mi)
        af[mi] = *(const bf16x8*)(As + buf * 8192 + (size_t)(wr * 64 + mi * 16 + (lane & 15)) * 64 + kk + k8);
      #pragma unroll
      for (int ni = 0; ni < 4; ++ni)
        bfrag[ni] = *(const bf16x8*)(Bs + buf * 8192 + (size_t)(wc * 64 + ni * 16 + (lane & 15)) * 64 + kk + k8);
      #pragma unroll
      for (int mi = 0; mi < 4; ++mi)
        #pragma unroll
        for (int ni = 0; ni < 4; ++ni)
          acc[mi][ni] = __builtin_amdgcn_mfma_f32_16x16x32_bf16(af[mi], bfrag[ni], acc[mi][ni], 0, 0, 0);
    }
    if (t < 23) {
      asm volatile("s_waitcnt vmcnt(0)" ::: "memory");
      writeA(buf ^ 1, alow(t + 1));
    }
    __syncthreads();
  }

  const bool isiou = (n0 < 768);  // block-uniform
  const int s_ = mtile;           // one s per m-tile (128 rows = all batches)
  #pragma unroll
  for (int ni = 0; ni < 4; ++ni) {
    int coln = n0 + wc * 64 + ni * 16 + (lane & 15);
    float bv = isiou ? biou[coln] : bfv[coln - 768];
    #pragma unroll
    for (int mi = 0; mi < 4; ++mi)
      #pragma unroll
      for (int r = 0; r < 4; ++r) {
        int bg = wr * 64 + mi * 16 + (lane >> 4) * 4 + r;
        float v = acc[mi][ni][r] + bv;
        if (isiou) gsum[((size_t)bg * 513 + s_) * 768 + coln] = v;
        else       xf[((size_t)s_ * 128 + bg) * 256 + (coln - 768)] = v;
      }
  }
}

// =============== scan: 8 groups x 16 batches; 8 col-split wgs (32 h-cols, 4 gates) ===============
// NO flags, NO cross-wg barrier: h published once per step into a per-step hx slot
// (agent-scope atomic stores); readers DATA-POLL the slot (poisoned 0xFF each call;
// valid h dwords can never carry exponent 0xFF since |h|<=1). gsum/fcsum/xf remain
// wg-private: WGP-scope atomic scatters + plain prefetch loads; one wg-local
// vmcnt(0)+barrier per step orders scatters before the next row prefetch.
__global__ __launch_bounds__(512, 1)
void scan_kernel(const unsigned short* __restrict__ ubh, const unsigned short* __restrict__ ubl,
                 const float* __restrict__ xf, const int* __restrict__ parents,
                 float* gsum, float* fcsum, unsigned* hx,
                 float* __restrict__ out)
{
  __shared__ __align__(16) unsigned short AH[8 * 64 * 8];   // A-frags hi: [kc][lane][8]
  __shared__ __align__(16) unsigned short AL[8 * 64 * 8];   // A-frags lo
  __shared__ float gcor[16 * 96];
  __shared__ float fcor[16 * 32];
  __shared__ float cbuf[16 * 32];
  __shared__ int   pbuf[2][16];
  __shared__ int   pl[16];

  const int bid = blockIdx.x;
  const int g = bid & 7, j = bid >> 3;   // group spread: members share bid%8
  const int tid = threadIdx.x;
  const int lane = tid & 63, w = tid >> 6;
  const int gb = g * 16;

  // ---- B-frag preload: wave w -> gate w>>1, col-half w&1 (16 cols) ----
  const int colb = (w >> 1) * 256 + j * 32 + (w & 1) * 16;
  const int bcol = colb + (lane & 15);
  const int bk8 = (lane >> 4) * 8;
  bf16x8 BH[8], BL[8];
  #pragma unroll
  for (int kc = 0; kc < 8; ++kc) {
    BH[kc] = *(const bf16x8*)(ubh + (size_t)bcol * 256 + kc * 32 + bk8);
    BL[kc] = *(const bf16x8*)(ubl + (size_t)bcol * 256 + kc * 32 + bk8);
  }

  // staging ids: thread -> (kc, lane-slot) -> (batch, k0)
  const int skc = tid >> 6, sl = tid & 63;
  const int sb = sl & 15, sk0 = skc * 32 + (sl >> 4) * 8;
  // activation ids
  const int ab = tid >> 5, ahc = tid & 31;
  const int abs_b = gb + ab, acol = j * 32 + ahc;
  // f ids
  const bool isf = (w >= 6);
  const int fr0 = (lane >> 4) * 4;
  const int fcl = (w & 1) * 16 + (lane & 15);

  if (tid < 16) { pbuf[0][tid] = parents[(gb + tid) * 512]; pl[tid] = -1; }

  float pre_i, pre_o, pre_u, fct_pre;
  {
    size_t gi0 = ((size_t)abs_b * 513) * 768 + acol;
    pre_i = gsum[gi0];
    pre_o = gsum[gi0 + 256];
    pre_u = gsum[gi0 + 512];
    fct_pre = fcsum[((size_t)abs_b * 513) * 256 + acol];
  }
  float xfv[4] = {0.f, 0.f, 0.f, 0.f};
  __syncthreads();

  #pragma unroll 1
  for (int s = 0; s < 512; ++s) {
    // ---- stage h(s-1): DATA-POLL per-step slot, unpack to AH/AL frag layout ----
    if (s > 0) {
      const unsigned long long* s64 =
          (const unsigned long long*)(hx + ((size_t)(s - 1) * 8 + g) * 4096 + sb * 256 + sk0);
      unsigned long long v0, v1, v2, v3;
      for (;;) {
        v0 = __hip_atomic_load(s64 + 0, RLX, AGT);
        v1 = __hip_atomic_load(s64 + 1, RLX, AGT);
        v2 = __hip_atomic_load(s64 + 2, RLX, AGT);
        v3 = __hip_atomic_load(s64 + 3, RLX, AGT);
        if (ok64(v0) && ok64(v1) && ok64(v2) && ok64(v3)) break;
      }
      u16x8 hiv, lov;
      unsigned long long vv[4] = {v0, v1, v2, v3};
      #pragma unroll
      for (int q = 0; q < 4; ++q) {
        unsigned lo32 = (unsigned)vv[q], hi32 = (unsigned)(vv[q] >> 32);
        hiv[2 * q]     = (unsigned short)(lo32 >> 16);
        lov[2 * q]     = (unsigned short)(lo32 & 0xffffu);
        hiv[2 * q + 1] = (unsigned short)(hi32 >> 16);
        lov[2 * q + 1] = (unsigned short)(hi32 & 0xffffu);
      }
      *(u16x8*)(AH + skc * 512 + sl * 8) = hiv;
      *(u16x8*)(AL + skc * 512 + sl * 8) = lov;
    }
    __syncthreads();   // stage barrier

    // ---- phase B: h(s-1) @ U (all 4 gates, 3-term split, 3 independent MFMA chains) ----
    if (s > 0) {
      f32x4 a0 = {0.f, 0.f, 0.f, 0.f};
      f32x4 a1 = {0.f, 0.f, 0.f, 0.f};
      f32x4 a2 = {0.f, 0.f, 0.f, 0.f};
      #pragma unroll
      for (int kc = 0; kc < 8; ++kc) {
        bf16x8 ah = *(const bf16x8*)(AH + kc * 512 + lane * 8);
        bf16x8 al = *(const bf16x8*)(AL + kc * 512 + lane * 8);
        a0 = __builtin_amdgcn_mfma_f32_16x16x32_bf16(ah, BH[kc], a0, 0, 0, 0);
        a1 = __builtin_amdgcn_mfma_f32_16x16x32_bf16(al, BH[kc], a1, 0, 0, 0);
        a2 = __builtin_amdgcn_mfma_f32_16x16x32_bf16(ah, BL[kc], a2, 0, 0, 0);
      }
      f32x4 acc = a0 + a1 + a2;
      if (!isf) {
        const int colg = colb + (lane & 15);
        const int colL = (w >> 1) * 32 + (w & 1) * 16 + (lane & 15);
        #pragma unroll
        for (int r = 0; r < 4; ++r) {
          int rb = fr0 + r;
          int p = pbuf[(s - 1) & 1][rb];
          if (p == s) gcor[rb * 96 + colL] = acc[r];
          else __hip_atomic_fetch_add(&gsum[((size_t)(gb + rb) * 513 + p) * 768 + colg],
                                      acc[r], RLX, WGP);   // wg-private: local-L2 atomic
        }
      } else {
        #pragma unroll
        for (int r = 0; r < 4; ++r) {
          int rb = fr0 + r;
          int p = pbuf[(s - 1) & 1][rb];
          float fg = sigm(xfv[r] + acc[r]);
          float fc = fg * cbuf[rb * 32 + fcl];
          if (p == s) fcor[rb * 32 + fcl] = fc;
          else __hip_atomic_fetch_add(&fcsum[((size_t)(gb + rb) * 513 + p) * 256 + j * 32 + fcl],
                                      fc, RLX, WGP);       // wg-private: local-L2 atomic
        }
        if (w == 6 && (lane & 15) == 0) {
          #pragma unroll
          for (int r = 0; r < 4; ++r) pl[fr0 + r] = pbuf[(s - 1) & 1][fr0 + r];
        }
      }
    }

    // ---- drain scatters (wg-local), then barrier: orders scatters/gcor/pl vs below ----
    asm volatile("s_waitcnt vmcnt(0)" ::: "memory");
    __syncthreads();

    // ---- activation for node s (all 512 threads: 16 b x 32 hc); publish h FIRST ----
    {
      bool corr = (pl[ab] == s);
      float gi = pre_i + (corr ? gcor[ab * 96 + ahc] : 0.f);
      float go = pre_o + (corr ? gcor[ab * 96 + 32 + ahc] : 0.f);
      float gu = pre_u + (corr ? gcor[ab * 96 + 64 + ahc] : 0.f);
      float fct = fct_pre + (corr ? fcor[ab * 32 + ahc] : 0.f);
      float c = sigm(gi) * tanhf(gu) + fct;
      float h = sigm(go) * tanhf(c);
      if (s < 511) {
        unsigned short hh = f2bf(h);
        unsigned short hl = f2bf(h - bf2f(hh));
        unsigned packed = ((unsigned)hh << 16) | hl;
        __hip_atomic_store(&hx[((size_t)s * 8 + g) * 4096 + ab * 256 + acol],
                           packed, RLX, AGT);   // coherence point: readers data-poll this
      }
      cbuf[ab * 32 + ahc] = c;
      out[((size_t)s * 128 + abs_b) * 256 + acol] = h;
      if (s == 511) out[(size_t)512 * 128 * 256 + (size_t)abs_b * 256 + acol] = h;
    }

    // ---- prefetch row s+1 (wg-private; ordered after this step's scatters by the
    //      drain barrier above) — overlaps the next stage poll ----
    if (s < 511) {
      const int sn = s + 1;
      {
        size_t gi1 = ((size_t)abs_b * 513 + sn) * 768 + acol;
        pre_i = gsum[gi1];
        pre_o = gsum[gi1 + 256];
        pre_u = gsum[gi1 + 512];
        fct_pre = fcsum[((size_t)abs_b * 513 + sn) * 256 + acol];
      }
      if (tid < 16) pbuf[sn & 1][tid] = parents[(gb + tid) * 512 + sn];
      if (isf) {
        #pragma unroll
        for (int r = 0; r < 4; ++r) {
          int p = pbuf[s & 1][fr0 + r];   // parents[.][s], loaded last iteration
          xfv[r] = (p < 512) ? xf[((size_t)p * 128 + (gb + fr0 + r)) * 256 + j * 32 + fcl] : 0.f;
        }
      }
    }
  }
}

extern "C" void kernel_launch(void* const* d_in, const int* in_sizes, int n_in,
                              void* d_out, int out_size, void* d_ws, size_t ws_size,
                              hipStream_t stream)
{
  (void)in_sizes; (void)n_in; (void)out_size; (void)ws_size;
  const float* inputs  = (const float*)d_in[0];
  const int*   parents = (const int*)d_in[1];
  const float* Wiou    = (const float*)d_in[2];
  const float* biou    = (const float*)d_in[3];
  const float* Uiou    = (const float*)d_in[4];
  const float* Wf      = (const float*)d_in[5];
  const float* bf_     = (const float*)d_in[6];
  const float* Uf      = (const float*)d_in[7];
  float* out = (float*)d_out;
  char* ws = (char*)d_ws;

  float* fcsum = (float*)(ws + OFF_FCSUM);
  unsigned* hx = (unsigned*)(ws + OFF_HX);
  float* gsum  = (float*)(ws + OFF_GSUM);
  float* xf    = (float*)(ws + OFF_XF);
  unsigned short* bth = (unsigned short*)(ws + OFF_BTH);
  unsigned short* btl = (unsigned short*)(ws + OFF_BTL);
  unsigned short* uh  = (unsigned short*)(ws + OFF_UH);
  unsigned short* ul  = (unsigned short*)(ws + OFF_UL);

  hipMemsetAsync(ws + OFF_FCSUM, 0, SZ_FCSUM, stream);      // fcsum zeros
  hipMemsetAsync(ws + OFF_HX, 0xFF, SZ_HX, stream);         // hx poison (invalid-exponent)

  hipFuncSetAttribute((const void*)gemm_split_kernel,
                      hipFuncAttributeMaxDynamicSharedMemorySize, 65536);

  cvt_w_kernel<<<2048, 256, 0, stream>>>(Wiou, Wf, bth, btl);
  cvt_u_kernel<<<1024, 256, 0, stream>>>(Uiou, Uf, uh, ul);
  gemm_split_kernel<<<4096, 256, 65536, stream>>>(inputs, bth, btl, biou, bf_, gsum, xf);
  scan_kernel<<<64, 512, 0, stream>>>(uh, ul, xf, parents, gsum, fcsum, hx, out);
}